// Round 3
// baseline (880.052 us; speedup 1.0000x reference)
//
#include <hip/hip_runtime.h>

// SepConv: out[b,c,i,j] = sum_{u,v} img[b,c,i+u,j+v] * vert[b,u,i,j] * hori[b,v,i,j]
// B=8, C=3, W=H=512, K=13, Wo=Ho=500.
//
// R3: latency fix v2. R2 showed weight staging was not the chain that hurts —
// the main-loop img loads are. Depth-2 software pipeline: issue u+1's 4 img
// float4 loads + vert float4 BEFORE the 52 FMAs of iteration u, so each load
// drain overlaps the previous iteration's FMA block. No LDS (R2 showed it
// neutral). __launch_bounds__(256,4) caps VGPR at 128 -> 4 waves/SIMD.

#define KK 13
#define NB 8
#define NC 3
#define IW 512
#define IH 512
#define WO 500
#define HO 500

__global__ __launch_bounds__(256, 4) void sepconv_kernel(
    const float* __restrict__ img,
    const float* __restrict__ hori,
    const float* __restrict__ vert,
    float* __restrict__ out)
{
    const int tj = threadIdx.x;                 // j-quad index within row
    const int i  = blockIdx.y * 2 + threadIdx.y;
    const int b  = blockIdx.z;
    if (tj >= HO / 4) return;                   // 125 quads; tx in [0,128)
    const int j0 = tj * 4;

    const size_t khw = (size_t)WO * HO;         // 250000
    const float* vbase = vert + (size_t)b * KK * khw + (size_t)i * HO + j0;
    const float* hbase = hori + (size_t)b * KK * khw + (size_t)i * HO + j0;

    #pragma unroll 1
    for (int c = 0; c < NC; ++c) {
        const float* ibase = img + (((size_t)(b * NC + c) * IW) + i) * IH + j0;

        float tmp[4][KK];
        #pragma unroll
        for (int jq = 0; jq < 4; ++jq)
            #pragma unroll
            for (int v = 0; v < KK; ++v)
                tmp[jq][v] = 0.0f;

        // ---- pipeline prologue: loads for u = 0 ----
        float4 c0 = *(const float4*)(ibase + 0);
        float4 c1 = *(const float4*)(ibase + 4);
        float4 c2 = *(const float4*)(ibase + 8);
        float4 c3 = *(const float4*)(ibase + 12);
        float4 vtc = *(const float4*)(vbase);

        #pragma unroll
        for (int u = 0; u < KK; ++u) {
            // ---- issue NEXT iteration's loads first (independent) ----
            float4 n0, n1, n2, n3, vtn;
            if (u < KK - 1) {
                const float* rp = ibase + (size_t)(u + 1) * IH;
                n0 = *(const float4*)(rp + 0);
                n1 = *(const float4*)(rp + 4);
                n2 = *(const float4*)(rp + 8);
                n3 = *(const float4*)(rp + 12);
                vtn = *(const float4*)(vbase + (size_t)(u + 1) * khw);
            }

            // ---- FMAs on CURRENT data (loaded one iteration ago) ----
            float row[16];
            row[0]  = c0.x; row[1]  = c0.y; row[2]  = c0.z; row[3]  = c0.w;
            row[4]  = c1.x; row[5]  = c1.y; row[6]  = c1.z; row[7]  = c1.w;
            row[8]  = c2.x; row[9]  = c2.y; row[10] = c2.z; row[11] = c2.w;
            row[12] = c3.x; row[13] = c3.y; row[14] = c3.z; row[15] = c3.w;

            #pragma unroll
            for (int v = 0; v < KK; ++v) {
                tmp[0][v] += row[0 + v] * vtc.x;
                tmp[1][v] += row[1 + v] * vtc.y;
                tmp[2][v] += row[2 + v] * vtc.z;
                tmp[3][v] += row[3 + v] * vtc.w;
            }

            if (u < KK - 1) {
                c0 = n0; c1 = n1; c2 = n2; c3 = n3; vtc = vtn;
            }
        }

        // ---- epilogue: fold hori ----
        float4 o = make_float4(0.f, 0.f, 0.f, 0.f);
        #pragma unroll
        for (int v = 0; v < KK; ++v) {
            const float4 hv = *(const float4*)(hbase + (size_t)v * khw);
            o.x += tmp[0][v] * hv.x;
            o.y += tmp[1][v] * hv.y;
            o.z += tmp[2][v] * hv.z;
            o.w += tmp[3][v] * hv.w;
        }

        float* op = out + (((size_t)(b * NC + c) * WO) + i) * HO + j0;
        *(float4*)op = o;
    }
}

extern "C" void kernel_launch(void* const* d_in, const int* in_sizes, int n_in,
                              void* d_out, int out_size, void* d_ws, size_t ws_size,
                              hipStream_t stream) {
    const float* img  = (const float*)d_in[0];
    const float* hori = (const float*)d_in[1];
    const float* vert = (const float*)d_in[2];
    float* out = (float*)d_out;

    // block: 128 j-quad lanes x 2 output rows; grid: y covers 500 rows / 2, z = batch
    dim3 block(128, 2, 1);
    dim3 grid(1, WO / 2, NB);
    hipLaunchKernelGGL(sepconv_kernel, grid, block, 0, stream, img, hori, vert, out);
}

// Round 4
// 358.509 us; speedup vs baseline: 2.4548x; 2.4548x over previous
//
#include <hip/hip_runtime.h>

// SepConv: out[b,c,i,j] = sum_{u,v} img[b,c,i+u,j+v] * vert[b,u,i,j] * hori[b,v,i,j]
// B=8, C=3, W=H=512, K=13, Wo=Ho=500.
//
// R4: hori-first algebra:  out = sum_u vert[u] * (sum_v img[i+u][j+v]*hori[v])
// -> accumulator is 4 floats, so all 26 weight quads (hori[13]+vert[13], the
// 208 MB always-HBM-cold stream) are preloaded in ONE batch of independent
// loads (single latency drain) and live in registers for all 3 channels.
// The u-loop's only memory ops are 4 L2/L3-warm img float4 loads.
// NO __launch_bounds__ min-waves (R3 spill lesson): let allocator take ~150.

#define KK 13
#define NB 8
#define NC 3
#define IW 512
#define IH 512
#define WO 500
#define HO 500

__global__ __launch_bounds__(256) void sepconv_kernel(
    const float* __restrict__ img,
    const float* __restrict__ hori,
    const float* __restrict__ vert,
    float* __restrict__ out)
{
    const int tj = threadIdx.x;                 // j-quad index within row
    const int i  = blockIdx.y * 2 + threadIdx.y;
    const int b  = blockIdx.z;
    if (tj >= HO / 4) return;                   // 125 quads; tx in [0,128)
    const int j0 = tj * 4;

    const size_t khw = (size_t)WO * HO;         // 250000
    const float* vbase = vert + (size_t)b * KK * khw + (size_t)i * HO + j0;
    const float* hbase = hori + (size_t)b * KK * khw + (size_t)i * HO + j0;

    // ---- bulk weight preload: 26 independent float4 loads, one drain ----
    float4 hw[KK], vw[KK];
    #pragma unroll
    for (int k = 0; k < KK; ++k) {
        hw[k] = *(const float4*)(hbase + (size_t)k * khw);
        vw[k] = *(const float4*)(vbase + (size_t)k * khw);
    }

    #pragma unroll 1
    for (int c = 0; c < NC; ++c) {
        const float* ibase = img + (((size_t)(b * NC + c) * IW) + i) * IH + j0;

        float4 acc = make_float4(0.f, 0.f, 0.f, 0.f);

        #pragma unroll
        for (int u = 0; u < KK; ++u) {
            const float* rp = ibase + (size_t)u * IH;
            const float4 r0 = *(const float4*)(rp + 0);
            const float4 r1 = *(const float4*)(rp + 4);
            const float4 r2 = *(const float4*)(rp + 8);
            const float4 r3 = *(const float4*)(rp + 12);

            float row[16];
            row[0]  = r0.x; row[1]  = r0.y; row[2]  = r0.z; row[3]  = r0.w;
            row[4]  = r1.x; row[5]  = r1.y; row[6]  = r1.z; row[7]  = r1.w;
            row[8]  = r2.x; row[9]  = r2.y; row[10] = r2.z; row[11] = r2.w;
            row[12] = r3.x; row[13] = r3.y; row[14] = r3.z; row[15] = r3.w;

            // horizontal conv with hori (weights in registers)
            float4 hs = make_float4(0.f, 0.f, 0.f, 0.f);
            #pragma unroll
            for (int v = 0; v < KK; ++v) {
                hs.x += row[0 + v] * hw[v].x;
                hs.y += row[1 + v] * hw[v].y;
                hs.z += row[2 + v] * hw[v].z;
                hs.w += row[3 + v] * hw[v].w;
            }
            // fold vert
            acc.x += hs.x * vw[u].x;
            acc.y += hs.y * vw[u].y;
            acc.z += hs.z * vw[u].z;
            acc.w += hs.w * vw[u].w;
        }

        float* op = out + (((size_t)(b * NC + c) * WO) + i) * HO + j0;
        *(float4*)op = acc;
    }
}

extern "C" void kernel_launch(void* const* d_in, const int* in_sizes, int n_in,
                              void* d_out, int out_size, void* d_ws, size_t ws_size,
                              hipStream_t stream) {
    const float* img  = (const float*)d_in[0];
    const float* hori = (const float*)d_in[1];
    const float* vert = (const float*)d_in[2];
    float* out = (float*)d_out;

    // block: 128 j-quad lanes x 2 output rows; grid: y covers 500 rows / 2, z = batch
    dim3 block(128, 2, 1);
    dim3 grid(1, WO / 2, NB);
    hipLaunchKernelGGL(sepconv_kernel, grid, block, 0, stream, img, hori, vert, out);
}

// Round 5
// 284.581 us; speedup vs baseline: 3.0924x; 1.2598x over previous
//
#include <hip/hip_runtime.h>

// SepConv: out[b,c,i,j] = sum_{u,v} img[b,c,i+u,j+v] * vert[b,u,i,j] * hori[b,v,i,j]
// B=8, C=3, W=H=512, K=13, Wo=Ho=500.
//
// R5: force memory-level parallelism. R1-R4 all latency-bound (~3 loads in
// flight per wave). Fixes:
//  - one channel per thread (lean ~110-reg live set, no spill risk)
//  - hori[13] quads preloaded as ONE independent 13-load burst, pinned with
//    sched_barrier(0) so the scheduler can't sink them to uses (R4 failure)
//  - u-loop: depth-2 manual prefetch of next img row (4x float4) + vert quad
//  - __launch_bounds__(256,3): VGPR cap 170 >> live set (R3 spilled when cap
//    was below the live set; never force a cap under it)

#define KK 13
#define NB 8
#define NC 3
#define IW 512
#define IH 512
#define WO 500
#define HO 500
#define QROW 125   // float4 quads per 500-col output row

__global__ __launch_bounds__(256, 3) void sepconv_kernel(
    const float* __restrict__ img,
    const float* __restrict__ hori,
    const float* __restrict__ vert,
    float* __restrict__ out)
{
    const int tj = threadIdx.x;                 // j-quad index
    if (tj >= QROW) return;
    const int i = blockIdx.y * 2 + threadIdx.y; // output row
    const int c = blockIdx.x;                   // channel
    const int b = blockIdx.z;                   // batch
    const int j0 = tj * 4;

    const size_t khw = (size_t)WO * HO;         // 250000
    const float* vbase = vert + (size_t)b * KK * khw + (size_t)i * HO + j0;
    const float* hbase = hori + (size_t)b * KK * khw + (size_t)i * HO + j0;

    // ---- hori preload: 13 independent float4 loads, one burst ----
    float4 hw[KK];
    #pragma unroll
    for (int v = 0; v < KK; ++v)
        hw[v] = *(const float4*)(hbase + (size_t)v * khw);
    // Pin: nothing (especially these loads) may be moved across this point.
    __builtin_amdgcn_sched_barrier(0);

    const float* ibase = img + (((size_t)(b * NC + c) * IW) + i) * IH + j0;

    // ---- pipeline prologue: u = 0 img row + vert quad ----
    float4 c0 = *(const float4*)(ibase + 0);
    float4 c1 = *(const float4*)(ibase + 4);
    float4 c2 = *(const float4*)(ibase + 8);
    float4 c3 = *(const float4*)(ibase + 12);
    float4 vtc = *(const float4*)(vbase);

    float4 acc = make_float4(0.f, 0.f, 0.f, 0.f);

    #pragma unroll
    for (int u = 0; u < KK; ++u) {
        // issue next iteration's 5 loads before this iteration's FMAs
        float4 n0, n1, n2, n3, vtn;
        if (u < KK - 1) {
            const float* rp = ibase + (size_t)(u + 1) * IH;
            n0  = *(const float4*)(rp + 0);
            n1  = *(const float4*)(rp + 4);
            n2  = *(const float4*)(rp + 8);
            n3  = *(const float4*)(rp + 12);
            vtn = *(const float4*)(vbase + (size_t)(u + 1) * khw);
        }

        float row[16];
        row[0]  = c0.x; row[1]  = c0.y; row[2]  = c0.z; row[3]  = c0.w;
        row[4]  = c1.x; row[5]  = c1.y; row[6]  = c1.z; row[7]  = c1.w;
        row[8]  = c2.x; row[9]  = c2.y; row[10] = c2.z; row[11] = c2.w;
        row[12] = c3.x; row[13] = c3.y; row[14] = c3.z; row[15] = c3.w;

        // horizontal conv (hori weights resident in regs), then fold vert
        float4 hs = make_float4(0.f, 0.f, 0.f, 0.f);
        #pragma unroll
        for (int v = 0; v < KK; ++v) {
            hs.x += row[0 + v] * hw[v].x;
            hs.y += row[1 + v] * hw[v].y;
            hs.z += row[2 + v] * hw[v].z;
            hs.w += row[3 + v] * hw[v].w;
        }
        acc.x += hs.x * vtc.x;
        acc.y += hs.y * vtc.y;
        acc.z += hs.z * vtc.z;
        acc.w += hs.w * vtc.w;

        if (u < KK - 1) {
            c0 = n0; c1 = n1; c2 = n2; c3 = n3; vtc = vtn;
        }
    }

    float* op = out + (((size_t)(b * NC + c) * WO) + i) * HO + j0;
    *(float4*)op = acc;
}

extern "C" void kernel_launch(void* const* d_in, const int* in_sizes, int n_in,
                              void* d_out, int out_size, void* d_ws, size_t ws_size,
                              hipStream_t stream) {
    const float* img  = (const float*)d_in[0];
    const float* hori = (const float*)d_in[1];
    const float* vert = (const float*)d_in[2];
    float* out = (float*)d_out;

    // block: 128 j-quad lanes x 2 output rows; grid: x=channel, y=row-pairs, z=batch
    dim3 block(128, 2, 1);
    dim3 grid(NC, WO / 2, NB);
    hipLaunchKernelGGL(sepconv_kernel, grid, block, 0, stream, img, hori, vert, out);
}

// Round 6
// 267.783 us; speedup vs baseline: 3.2864x; 1.0627x over previous
//
#include <hip/hip_runtime.h>

// SepConv: out[b,c,i,j] = sum_{u,v} img[b,c,i+u,j+v] * vert[b,u,i,j] * hori[b,v,i,j]
// B=8, C=3, W=H=512, K=13, Wo=Ho=500.
//
// R6: weights via fire-and-forget LDS DMA. R1-R5 showed (a) the allocator
// always sinks register-resident weight preloads (R4/R5: VGPR 88/68), and
// (b) per-iteration weight loads are cold-HBM (~900cyc) and latency-bound.
// global_load_lds(width=16) fixes both: no VGPR round-trip (nothing to
// sink), one bulk drain for all 52KB of this row's weights, and the compute
// loop reads them at ds_read_b128 cost. img loads keep R5's depth-1
// prefetch (L2/L3-warm, hideable). tmp[4][13] accumulators (R1 algebra)
// are un-sinkable by construction. 52KB/block -> 3 blocks/CU so staging
// DMA of one block overlaps compute of another.

#define KK 13
#define NB 8
#define NC 3
#define IW 512
#define IH 512
#define WO 500
#define HO 500
#define QROW 125              // float4 quads per 500-col row
#define NT 384                // 128 j-lanes x 3 channels
#define NQ (KK * QROW)        // 1625 float4s per weight array

typedef __attribute__((address_space(1))) const void g_void;
typedef __attribute__((address_space(3))) void l_void;

__global__ __launch_bounds__(NT) void sepconv_kernel(
    const float* __restrict__ img,
    const float* __restrict__ hori,
    const float* __restrict__ vert,
    float* __restrict__ out)
{
    __shared__ float4 s_vert[NQ];   // [u][quad], 26000 B
    __shared__ float4 s_hori[NQ];   // [v][quad], 26000 B

    const int tid = threadIdx.y * 128 + threadIdx.x;
    const int i = blockIdx.x;       // output row
    const int b = blockIdx.y;       // batch

    const size_t khw = (size_t)WO * HO;      // 250000
    const size_t rs4 = khw / 4;              // 62500 float4 between k-slices
    const float4* vsrc = (const float4*)(vert + (size_t)b * KK * khw + (size_t)i * HO);
    const float4* hsrc = (const float4*)(hori + (size_t)b * KK * khw + (size_t)i * HO);

    // ---- stage weights: pure DMA, no VGPR round-trip, deep MLP ----
    // Each wave's 64 lanes cover contiguous f -> contiguous LDS chunk
    // (global_load_lds dest = wave-uniform base + lane*16).
    #pragma unroll
    for (int f0 = 0; f0 < NQ; f0 += NT) {
        const int f = f0 + tid;
        if (f < NQ) {
            const unsigned u = (unsigned)f / QROW;
            const unsigned q = (unsigned)f - u * QROW;
            __builtin_amdgcn_global_load_lds(
                (g_void*)(vsrc + (size_t)u * rs4 + q),
                (l_void*)&s_vert[f], 16, 0, 0);
            __builtin_amdgcn_global_load_lds(
                (g_void*)(hsrc + (size_t)u * rs4 + q),
                (l_void*)&s_hori[f], 16, 0, 0);
        }
    }
    __syncthreads();   // vmcnt(0) drain + barrier

    const int tj = threadIdx.x;     // j-quad
    const int c  = threadIdx.y;     // channel
    if (tj >= QROW) return;
    const int j0 = tj * 4;

    const float* ibase = img + (((size_t)(b * NC + c) * IW) + i) * IH + j0;

    float tmp[4][KK];
    #pragma unroll
    for (int jq = 0; jq < 4; ++jq)
        #pragma unroll
        for (int v = 0; v < KK; ++v)
            tmp[jq][v] = 0.0f;

    // ---- pipeline prologue: img row u = 0 ----
    float4 c0 = *(const float4*)(ibase + 0);
    float4 c1 = *(const float4*)(ibase + 4);
    float4 c2 = *(const float4*)(ibase + 8);
    float4 c3 = *(const float4*)(ibase + 12);

    #pragma unroll
    for (int u = 0; u < KK; ++u) {
        // issue next img row before this iteration's FMAs
        float4 n0, n1, n2, n3;
        if (u < KK - 1) {
            const float* rp = ibase + (size_t)(u + 1) * IH;
            n0 = *(const float4*)(rp + 0);
            n1 = *(const float4*)(rp + 4);
            n2 = *(const float4*)(rp + 8);
            n3 = *(const float4*)(rp + 12);
        }

        const float4 vt = s_vert[u * QROW + tj];   // ds_read_b128

        float row[16];
        row[0]  = c0.x; row[1]  = c0.y; row[2]  = c0.z; row[3]  = c0.w;
        row[4]  = c1.x; row[5]  = c1.y; row[6]  = c1.z; row[7]  = c1.w;
        row[8]  = c2.x; row[9]  = c2.y; row[10] = c2.z; row[11] = c2.w;
        row[12] = c3.x; row[13] = c3.y; row[14] = c3.z; row[15] = c3.w;

        #pragma unroll
        for (int v = 0; v < KK; ++v) {
            tmp[0][v] += row[0 + v] * vt.x;
            tmp[1][v] += row[1 + v] * vt.y;
            tmp[2][v] += row[2 + v] * vt.z;
            tmp[3][v] += row[3 + v] * vt.w;
        }

        if (u < KK - 1) {
            c0 = n0; c1 = n1; c2 = n2; c3 = n3;
        }
    }

    // ---- epilogue: fold hori from LDS ----
    float4 o = make_float4(0.f, 0.f, 0.f, 0.f);
    #pragma unroll
    for (int v = 0; v < KK; ++v) {
        const float4 hv = s_hori[v * QROW + tj];
        o.x += tmp[0][v] * hv.x;
        o.y += tmp[1][v] * hv.y;
        o.z += tmp[2][v] * hv.z;
        o.w += tmp[3][v] * hv.w;
    }

    float* op = out + (((size_t)(b * NC + c) * WO) + i) * HO + j0;
    *(float4*)op = o;
}

extern "C" void kernel_launch(void* const* d_in, const int* in_sizes, int n_in,
                              void* d_out, int out_size, void* d_ws, size_t ws_size,
                              hipStream_t stream) {
    const float* img  = (const float*)d_in[0];
    const float* hori = (const float*)d_in[1];
    const float* vert = (const float*)d_in[2];
    float* out = (float*)d_out;

    dim3 block(128, 3, 1);        // x = j-quads (125 used), y = channel
    dim3 grid(WO, NB, 1);         // x = output row i, y = batch
    hipLaunchKernelGGL(sepconv_kernel, grid, block, 0, stream, img, hori, vert, out);
}